// Round 6
// baseline (418.102 us; speedup 1.0000x reference)
//
#include <hip/hip_runtime.h>
#include <stdint.h>

typedef __attribute__((ext_vector_type(4))) int int4v;
typedef __attribute__((ext_vector_type(16))) int int16v;
typedef __attribute__((ext_vector_type(4))) uint32_t uint4v;

#define M_DIM 8192
#define N_DIM 4096
#define K_DIM 4096

// K-permuted layout: within each 64-byte K chunk, stored byte p holds
// original k = (p>>2) + 16*(p&3). Applied identically to A and B => MFMA
// dot products unchanged.
// GEMM LDS: 2 buffers x 64 KiB (A 32K @ +0, B 32K @ +32768). Each 32K holds
// 256 rows x 128 B slot-major per 16-row window:
//   off(row, slot) = (row>>4)*2048 + (slot>>2)*1024 + (slot&3)*256 + (row&15)*16
// One async16 covers one (window, slot-half): lane l -> row=l&15, slot-in-half
// =l>>4; LDS dest is linear (base + 16*l), global side consumes whole 64-B
// lines (coalesced), fragment reads are 256-B contiguous per 16 lanes (0 bank
// conflicts). Schedule: 4 phases/tile (kh,mh quadrants), 1 barrier/phase,
// stage 2 loads/phase for tile t+1, vmcnt(4) at ends of phases 2 & 4 retiring
// loads issued 2-3 phases earlier (~1200+ cyc HBM-latency cover).

// ---------------- pack x: int32 -> int8, K-permuted ----------------
__global__ void pack_a_perm(const int* __restrict__ x, uint4v* __restrict__ a8) {
    const int g = blockIdx.x * blockDim.x + threadIdx.x;  // global 16-B word index
    const int w0 = (g & 3) * 4;                           // word slot within chunk
    const int chunk = g >> 2;                             // 64-element k chunk
    const int* base = x + (size_t)chunk * 64;
    int4v L[4];
#pragma unroll
    for (int j = 0; j < 4; ++j) L[j] = *(const int4v*)(base + j * 16 + w0);
    uint4v outv;
#pragma unroll
    for (int wi = 0; wi < 4; ++wi) {
        outv[wi] = (uint32_t)(L[0][wi] & 0xff) | ((uint32_t)(L[1][wi] & 0xff) << 8) |
                   ((uint32_t)(L[2][wi] & 0xff) << 16) | ((uint32_t)(L[3][wi] & 0xff) << 24);
    }
    a8[g] = outv;
}

// ------- transpose+pack weight: [K][N] int32 -> Bt[N][K-permuted] int8 -------
__global__ void transpose_b_perm(const int* __restrict__ w, int8_t* __restrict__ bt) {
    const int t = threadIdx.x;
    const int kt = blockIdx.y * 64;
    const int n0 = blockIdx.x * 64;
    const int c4 = t & 3;
    const int n = t >> 2;
    const int w0 = c4 * 4;
    const int* col = w + (size_t)kt * N_DIM + n0 + n;
    uint4v outv;
#pragma unroll
    for (int wi = 0; wi < 4; ++wi) {
        uint32_t p = 0;
#pragma unroll
        for (int j = 0; j < 4; ++j) {
            uint32_t b = (uint32_t)(col[(size_t)(w0 + wi + 16 * j) * N_DIM] & 0xff);
            p |= b << (8 * j);
        }
        outv[wi] = p;
    }
    *(uint4v*)&bt[(size_t)(n0 + n) * K_DIM + kt + w0 * 4] = outv;
}

// -------- GEMM: 256x256 tile, BK=128, 4-phase/tile, slot-major LDS --------
__device__ inline void async16(const void* g, void* l) {
    __builtin_amdgcn_global_load_lds(
        (const __attribute__((address_space(1))) uint32_t*)g,
        (__attribute__((address_space(3))) uint32_t*)l, 16, 0, 0);
}

#define SB() __builtin_amdgcn_sched_barrier(0)
#define BAR() do { SB(); __builtin_amdgcn_s_barrier(); SB(); } while (0)

__global__ void __launch_bounds__(512, 2)
gemm_kernel(const int8_t* __restrict__ A, const int8_t* __restrict__ Bt,
            const float* __restrict__ pa, const float* __restrict__ pb,
            int* __restrict__ out) {
    __shared__ int8_t smem[131072];   // 2 x (A 32K + B 32K)

    const int t = threadIdx.x;
    const int lane = t & 63;
    const int wave = t >> 6;

    // XCD-aware bijective swizzle (nwg = 512, divisible by 8)
    int wg = (int)blockIdx.x;
    wg = (wg & 7) * 64 + (wg >> 3);
    const int bx = wg & 15;         // N / 256 = 16
    const int by = wg >> 4;         // M / 256 = 32
    const int m0 = by * 256;
    const int n0 = bx * 256;

    const int wm = (wave >> 2) * 128;   // 2 waves along M
    const int wn = (wave & 3) * 64;     // 4 waves along N
    const float scale = pa[0] * pb[0];

    // ---- staging: wave w owns rows 32w..32w+31 (2 windows) of A and of B.
    // Lane l -> row base + (l&15), 16-B sub-slot (l>>4) of a 64-B half.
    const int srow = 32 * wave + (lane & 15);
    const int shalf = (lane >> 4) * 16;
    const int8_t* pA = A + (size_t)(m0 + srow) * K_DIM + shalf;
    const int8_t* pB = Bt + (size_t)(n0 + srow) * K_DIM + shalf;
    const int ldsA = wave * 4096;            // wave-uniform dests
    const int ldsB = 32768 + wave * 4096;    // +1024 for hi half, +2048 for 2nd window

    // ---- fragment-read bases ----
    const int rl = lane & 31;
    const int hlp = (lane >> 5) * 256;       // 16-B half of K=32 window
    const int raB = ((wm + rl) >> 4) * 2048 + (rl & 15) * 16 + hlp;
    const int rbB = 32768 + ((wn + rl) >> 4) * 2048 + (rl & 15) * 16 + hlp;
    // + mh*8192 (A) / j*4096 (B) / i*4096 (A) / kh*1024 / kw*512

    int16v acc[4][2];
#pragma unroll
    for (int mi = 0; mi < 4; ++mi)
#pragma unroll
        for (int j = 0; j < 2; ++j)
#pragma unroll
            for (int r = 0; r < 16; ++r) acc[mi][j][r] = 0;

    int4v afX[2][2], afY[2][2], bfX[2][2];

#define ST2(P, LDSOFF, TT, H) do {                                        \
        const int b_ = ((TT) & 1) * 65536;                                \
        const int kt_ = ((TT) & 31) * 128 + (H) * 64; /* wrap: dead */    \
        async16((P) + kt_, smem + b_ + (LDSOFF) + (H) * 1024);            \
        async16((P) + kt_ + (size_t)16 * K_DIM,                           \
                smem + b_ + (LDSOFF) + (H) * 1024 + 2048);                \
    } while (0)

#define RD_A(AF, BUF, KH, MH) do {                                        \
        const int a_ = (BUF) * 65536 + raB + (MH) * 8192 + (KH) * 1024;   \
        AF[0][0] = *(const int4v*)&smem[a_ + 0 * 4096 + 0 * 512];         \
        AF[0][1] = *(const int4v*)&smem[a_ + 0 * 4096 + 1 * 512];         \
        AF[1][0] = *(const int4v*)&smem[a_ + 1 * 4096 + 0 * 512];         \
        AF[1][1] = *(const int4v*)&smem[a_ + 1 * 4096 + 1 * 512];         \
    } while (0)

#define RD_B(BF, BUF, KH) do {                                            \
        const int a_ = (BUF) * 65536 + rbB + (KH) * 1024;                 \
        BF[0][0] = *(const int4v*)&smem[a_ + 0 * 4096 + 0 * 512];         \
        BF[0][1] = *(const int4v*)&smem[a_ + 0 * 4096 + 1 * 512];         \
        BF[1][0] = *(const int4v*)&smem[a_ + 1 * 4096 + 0 * 512];         \
        BF[1][1] = *(const int4v*)&smem[a_ + 1 * 4096 + 1 * 512];         \
    } while (0)

#define MM8(AF, BF, MH) do {                                              \
        __builtin_amdgcn_s_setprio(1);                                    \
        _Pragma("unroll")                                                 \
        for (int kw = 0; kw < 2; ++kw)                                    \
            _Pragma("unroll")                                             \
            for (int i = 0; i < 2; ++i)                                   \
                _Pragma("unroll")                                         \
                for (int j = 0; j < 2; ++j)                               \
                    acc[(MH) * 2 + i][j] = __builtin_amdgcn_mfma_i32_32x32x32_i8( \
                        AF[i][kw], BF[j][kw], acc[(MH) * 2 + i][j], 0, 0, 0); \
        __builtin_amdgcn_s_setprio(0);                                    \
    } while (0)

    // ---- prologue: stage tile 0 (order B-lo, A-lo, B-hi, A-hi) ----
    ST2(pB, ldsB, 0, 0); ST2(pA, ldsA, 0, 0);
    ST2(pB, ldsB, 0, 1); ST2(pA, ldsA, 0, 1);
    asm volatile("s_waitcnt vmcnt(4)" ::: "memory");   // B-lo,A-lo of tile 0
    BAR();

    // Steady ledger per wave (8 loads/tile, 2/phase):
    //  end P2: vmcnt(4) retires {B-hi,A-hi}(tt)   [issued P3,P4 of tt-1]
    //  end P4: vmcnt(4) retires {B-lo,A-lo}(tt+1) [issued P1,P2 of tt]
#pragma unroll 1
    for (int tt = 0; tt < 32; ++tt) {
        const int c = tt & 1;
        // ---- P1 (kh0, mh0): stage B-lo(tt+1); read cur + P2's A-frags
        ST2(pB, ldsB, tt + 1, 0);
        RD_A(afX, c, 0, 0); RD_B(bfX, c, 0);
        RD_A(afY, c, 0, 1);
        SB();
        asm volatile("s_waitcnt lgkmcnt(4)" ::: "memory");  // cur 8 done, afY in flight
        SB();
        MM8(afX, bfX, 0);
        BAR();
        // ---- P2 (kh0, mh1): stage A-lo(tt+1); MFMA on prefetched afY
        ST2(pA, ldsA, tt + 1, 0);
        SB();
        asm volatile("s_waitcnt lgkmcnt(0)" ::: "memory");  // afY done long ago
        SB();
        MM8(afY, bfX, 1);
        asm volatile("s_waitcnt vmcnt(4)" ::: "memory");    // hi-slots of tt landed
        BAR();
        // ---- P3 (kh1, mh0): stage B-hi(tt+1); read cur + P4's A-frags
        ST2(pB, ldsB, tt + 1, 1);
        RD_A(afX, c, 1, 0); RD_B(bfX, c, 1);
        RD_A(afY, c, 1, 1);
        SB();
        asm volatile("s_waitcnt lgkmcnt(4)" ::: "memory");
        SB();
        MM8(afX, bfX, 0);
        BAR();
        // ---- P4 (kh1, mh1): stage A-hi(tt+1); MFMA on prefetched afY
        ST2(pA, ldsA, tt + 1, 1);
        SB();
        asm volatile("s_waitcnt lgkmcnt(0)" ::: "memory");
        SB();
        MM8(afY, bfX, 1);
        asm volatile("s_waitcnt vmcnt(4)" ::: "memory");    // lo-slots of tt+1 landed
        BAR();
    }

    // Drain: no DMA may outlive the workgroup (next block reuses this LDS).
    asm volatile("s_waitcnt vmcnt(0) lgkmcnt(0)" ::: "memory");

    // ---- epilogue: dequant + saturate + store ----
    const int col = lane & 31;
    const int rbase = (lane >> 5) * 4;
#pragma unroll
    for (int mi = 0; mi < 4; ++mi)
#pragma unroll
        for (int j = 0; j < 2; ++j)
#pragma unroll
            for (int r = 0; r < 16; ++r) {
                const int rowf = rbase + (r & 3) + 8 * (r >> 2);
                float v = (float)acc[mi][j][r] * scale;
                v = rintf(v);
                v = fminf(127.f, fmaxf(-128.f, v));
                out[(size_t)(m0 + wm + mi * 32 + rowf) * N_DIM +
                    (n0 + wn + j * 32 + col)] = (int)v;
            }
#undef ST2
#undef RD_A
#undef RD_B
#undef MM8
}

extern "C" void kernel_launch(void* const* d_in, const int* in_sizes, int n_in,
                              void* d_out, int out_size, void* d_ws, size_t ws_size,
                              hipStream_t stream) {
    const int* x = (const int*)d_in[0];
    const int* w = (const int*)d_in[1];
    const float* pa = (const float*)d_in[2];
    const float* pb = (const float*)d_in[3];
    int* out = (int*)d_out;

    int8_t* a8 = (int8_t*)d_ws;                       // 32 MiB
    int8_t* bt8 = a8 + (size_t)M_DIM * K_DIM;         // 16 MiB

    const int nwords_a = M_DIM * K_DIM / 16;
    pack_a_perm<<<nwords_a / 256, 256, 0, stream>>>(x, (uint4v*)a8);
    transpose_b_perm<<<dim3(N_DIM / 64, K_DIM / 64), 256, 0, stream>>>(w, bt8);
    gemm_kernel<<<dim3(512), dim3(512), 0, stream>>>(a8, bt8, pa, pb, out);
}